// Round 1
// baseline (997.123 us; speedup 1.0000x reference)
//
#include <hip/hip_runtime.h>
#include <math.h>

#define NN 64000      // nodes
#define NE 1024000    // edges
#define NB 4000       // sequences
#define NT 16         // timesteps

__device__ __forceinline__ float sigm(float x) { return 1.0f / (1.0f + expf(-x)); }

// ---------- degree / norm ----------
__global__ __launch_bounds__(256) void k_deg_init(float* __restrict__ deg) {
    int i = blockIdx.x * 256 + threadIdx.x;
    if (i < NN) deg[i] = 1.0f;
}

__global__ __launch_bounds__(256) void k_deg_accum(const int* __restrict__ ei,
                                                   const float* __restrict__ ew,
                                                   float* __restrict__ deg) {
    int e = blockIdx.x * 256 + threadIdx.x;
    if (e < NE) atomicAdd(&deg[ei[NE + e]], ew[e]);
}

__global__ __launch_bounds__(256) void k_dinv(float* __restrict__ deg) {
    int i = blockIdx.x * 256 + threadIdx.x;
    if (i < NN) deg[i] = rsqrtf(deg[i]);
}

__global__ __launch_bounds__(256) void k_norm(const int* __restrict__ ei,
                                              const float* __restrict__ ew,
                                              const float* __restrict__ dinv,
                                              float* __restrict__ nrm) {
    int e = blockIdx.x * 256 + threadIdx.x;
    if (e < NE) nrm[e] = dinv[ei[e]] * ew[e] * dinv[ei[NE + e]];
}

// ---------- node linear: Y[n][64] = (relu?)X[n][:K] @ W[K][64] ----------
template<int K, bool RELU_IN>
__global__ __launch_bounds__(256) void k_lin(const float* __restrict__ X,
                                             const float* __restrict__ W,
                                             float* __restrict__ Y) {
    __shared__ float Wl[K * 64];
    __shared__ float Xl[4][K];
    int tid = threadIdx.x;
    for (int i = tid; i < K * 64; i += 256) Wl[i] = W[i];
    int n0 = blockIdx.x * 4;
    for (int i = tid; i < 4 * K; i += 256) {
        int r = i / K, d = i % K;
        float v = X[(n0 + r) * K + d];
        Xl[r][d] = RELU_IN ? fmaxf(v, 0.0f) : v;
    }
    __syncthreads();
    int r = tid >> 6, f = tid & 63;
    float acc = 0.0f;
    #pragma unroll
    for (int d = 0; d < K; ++d) acc = fmaf(Xl[r][d], Wl[d * 64 + f], acc);
    Y[(n0 + r) * 64 + f] = acc;
}

// ---------- agg init: agg = lin*dinv^2 + bias ----------
__global__ __launch_bounds__(256) void k_agg_init(const float* __restrict__ lin,
                                                  const float* __restrict__ dinv,
                                                  const float* __restrict__ b,
                                                  float* __restrict__ agg) {
    int i = blockIdx.x * 256 + threadIdx.x;   // i < NN*64
    int n = i >> 6, f = i & 63;
    float di = dinv[n];
    agg[i] = lin[i] * di * di + b[f];
}

// ---------- edge scatter: agg[col] += norm * lin[row] ----------
__global__ __launch_bounds__(256) void k_scatter(const int* __restrict__ ei,
                                                 const float* __restrict__ nrm,
                                                 const float* __restrict__ lin,
                                                 float* __restrict__ agg) {
    int tid = threadIdx.x;
    int e = blockIdx.x * 4 + (tid >> 6);
    int f = tid & 63;
    int r = ei[e];
    int c = ei[NE + e];
    float w = nrm[e];
    atomicAdd(&agg[c * 64 + f], w * lin[r * 64 + f]);
}

// ---------- LSTM weight prep: Wt[k][g], k<64 from W_ih, else W_hh; biasc ----------
__global__ __launch_bounds__(256) void k_wprep(const float* __restrict__ W_ih,
                                               const float* __restrict__ W_hh,
                                               const float* __restrict__ b_ih,
                                               const float* __restrict__ b_hh,
                                               float* __restrict__ Wt,
                                               float* __restrict__ biasc) {
    int i = blockIdx.x * 256 + threadIdx.x;
    if (i < 192 * 512) {
        int k = i >> 9, g = i & 511;
        Wt[i] = (k < 64) ? W_ih[g * 64 + k] : W_hh[g * 128 + (k - 64)];
    }
    if (i < 512) biasc[i] = b_ih[i] + b_hh[i];
}

// ---------- LSTM: 16 rows/block through all 16 steps, h/c in LDS ----------
__global__ __launch_bounds__(512) void k_lstm(const float* __restrict__ seq,   // pre-relu (NN x 64)
                                              const float* __restrict__ Wt,    // [192][512]
                                              const float* __restrict__ biasc, // [512]
                                              float* __restrict__ hout) {      // [NB][128]
    __shared__ float At[192][16];
    __shared__ float hs[16][128];
    __shared__ float cs[16][128];
    __shared__ float gs[16][512];
    int tid = threadIdx.x;
    int b0 = blockIdx.x * 16;
    for (int i = tid; i < 16 * 128; i += 512) {
        int r = i >> 7, k = i & 127;
        hs[r][k] = 0.0f; cs[r][k] = 0.0f;
    }
    int lane = tid & 63;
    int wq = tid >> 6;       // 0..7
    int g0 = lane << 3;      // gate group of 8
    int r0 = wq << 1;        // row pair
    float bj[8];
    #pragma unroll
    for (int j = 0; j < 8; ++j) bj[j] = biasc[g0 + j];
    __syncthreads();

    for (int t = 0; t < NT; ++t) {
        // build A^T = [relu(seq_t) | h] transposed: At[k][r]
        for (int i = tid; i < 64 * 16; i += 512) {
            int r = i >> 6, k = i & 63;
            At[k][r] = fmaxf(seq[((b0 + r) * NT + t) * 64 + k], 0.0f);
        }
        for (int i = tid; i < 128 * 16; i += 512) {
            int r = i >> 7, k = i & 127;
            At[64 + k][r] = hs[r][k];
        }
        __syncthreads();

        float acc0[8], acc1[8];
        #pragma unroll
        for (int j = 0; j < 8; ++j) { acc0[j] = bj[j]; acc1[j] = bj[j]; }
        #pragma unroll 4
        for (int k = 0; k < 192; ++k) {
            float2 a = *(const float2*)&At[k][r0];
            const float4 w0 = *(const float4*)&Wt[(k << 9) + g0];
            const float4 w1 = *(const float4*)&Wt[(k << 9) + g0 + 4];
            acc0[0] = fmaf(a.x, w0.x, acc0[0]);
            acc0[1] = fmaf(a.x, w0.y, acc0[1]);
            acc0[2] = fmaf(a.x, w0.z, acc0[2]);
            acc0[3] = fmaf(a.x, w0.w, acc0[3]);
            acc0[4] = fmaf(a.x, w1.x, acc0[4]);
            acc0[5] = fmaf(a.x, w1.y, acc0[5]);
            acc0[6] = fmaf(a.x, w1.z, acc0[6]);
            acc0[7] = fmaf(a.x, w1.w, acc0[7]);
            acc1[0] = fmaf(a.y, w0.x, acc1[0]);
            acc1[1] = fmaf(a.y, w0.y, acc1[1]);
            acc1[2] = fmaf(a.y, w0.z, acc1[2]);
            acc1[3] = fmaf(a.y, w0.w, acc1[3]);
            acc1[4] = fmaf(a.y, w1.x, acc1[4]);
            acc1[5] = fmaf(a.y, w1.y, acc1[5]);
            acc1[6] = fmaf(a.y, w1.z, acc1[6]);
            acc1[7] = fmaf(a.y, w1.w, acc1[7]);
        }
        *(float4*)&gs[r0][g0]       = make_float4(acc0[0], acc0[1], acc0[2], acc0[3]);
        *(float4*)&gs[r0][g0 + 4]   = make_float4(acc0[4], acc0[5], acc0[6], acc0[7]);
        *(float4*)&gs[r0 + 1][g0]     = make_float4(acc1[0], acc1[1], acc1[2], acc1[3]);
        *(float4*)&gs[r0 + 1][g0 + 4] = make_float4(acc1[4], acc1[5], acc1[6], acc1[7]);
        __syncthreads();

        for (int i = tid; i < 16 * 128; i += 512) {
            int r = i >> 7, kk = i & 127;
            float ig = gs[r][kk];
            float fg = gs[r][kk + 128];
            float gg = gs[r][kk + 256];
            float og = gs[r][kk + 384];
            float cc = cs[r][kk];
            float nc = sigm(fg) * cc + sigm(ig) * tanhf(gg);
            cs[r][kk] = nc;
            hs[r][kk] = sigm(og) * tanhf(nc);
        }
        __syncthreads();
    }
    for (int i = tid; i < 16 * 128; i += 512) {
        int r = i >> 7, k = i & 127;
        hout[(b0 + r) * 128 + k] = hs[r][k];
    }
}

// ---------- FC head + softmax: one wave per row ----------
__global__ __launch_bounds__(256) void k_fc(const float* __restrict__ h,
                                            const float* __restrict__ fw1,
                                            const float* __restrict__ fb1,
                                            const float* __restrict__ fw2,
                                            const float* __restrict__ fb2,
                                            float* __restrict__ out) {
    __shared__ float hid[4][64];
    int tid = threadIdx.x;
    int lane = tid & 63;
    int w = tid >> 6;
    int b = blockIdx.x * 4 + w;
    const float* hr = h + b * 128;
    float acc = fb1[lane];
    #pragma unroll 4
    for (int k = 0; k < 128; ++k) acc = fmaf(hr[k], fw1[k * 64 + lane], acc);
    hid[w][lane] = fmaxf(acc, 0.0f);
    __syncthreads();
    if (lane == 0) {
        float lg[3];
        #pragma unroll
        for (int l = 0; l < 3; ++l) {
            float a = fb2[l];
            for (int j = 0; j < 64; ++j) a = fmaf(hid[w][j], fw2[j * 3 + l], a);
            lg[l] = a;
        }
        float m = fmaxf(lg[0], fmaxf(lg[1], lg[2]));
        float e0 = expf(lg[0] - m), e1 = expf(lg[1] - m), e2 = expf(lg[2] - m);
        float s = 1.0f / (e0 + e1 + e2);
        out[b * 3 + 0] = e0 * s;
        out[b * 3 + 1] = e1 * s;
        out[b * 3 + 2] = e2 * s;
    }
}

extern "C" void kernel_launch(void* const* d_in, const int* in_sizes, int n_in,
                              void* d_out, int out_size, void* d_ws, size_t ws_size,
                              hipStream_t stream) {
    const float* x    = (const float*)d_in[0];
    const float* ea   = (const float*)d_in[1];
    const float* W1   = (const float*)d_in[2];
    const float* b1   = (const float*)d_in[3];
    const float* W2   = (const float*)d_in[4];
    const float* b2   = (const float*)d_in[5];
    const float* W_ih = (const float*)d_in[6];
    const float* W_hh = (const float*)d_in[7];
    const float* b_ih = (const float*)d_in[8];
    const float* b_hh = (const float*)d_in[9];
    const float* fw1  = (const float*)d_in[10];
    const float* fb1  = (const float*)d_in[11];
    const float* fw2  = (const float*)d_in[12];
    const float* fb2  = (const float*)d_in[13];
    const int*   ei   = (const int*)d_in[14];
    float* out = (float*)d_out;

    float* ws    = (float*)d_ws;
    float* dinv  = ws;                    // 64,000
    float* nrm   = dinv + NN;             // 1,024,000
    float* bufA  = nrm + NE;              // 4,096,000
    float* bufB  = bufA + NN * 64;        // 4,096,000
    float* Wt    = bufB + NN * 64;        // 98,304
    float* biasc = Wt + 192 * 512;        // 512
    float* hbuf  = biasc + 512;           // 512,000

    // degree / norm (shared by both GCN layers)
    k_deg_init<<<250, 256, 0, stream>>>(dinv);
    k_deg_accum<<<4000, 256, 0, stream>>>(ei, ea, dinv);
    k_dinv<<<250, 256, 0, stream>>>(dinv);
    k_norm<<<4000, 256, 0, stream>>>(ei, ea, dinv, nrm);
    k_wprep<<<384, 256, 0, stream>>>(W_ih, W_hh, b_ih, b_hh, Wt, biasc);

    // GCN layer 1
    k_lin<16, false><<<16000, 256, 0, stream>>>(x, W1, bufA);
    k_agg_init<<<16000, 256, 0, stream>>>(bufA, dinv, b1, bufB);
    k_scatter<<<256000, 256, 0, stream>>>(ei, nrm, bufA, bufB);

    // GCN layer 2 (relu of layer-1 output fused into read)
    k_lin<64, true><<<16000, 256, 0, stream>>>(bufB, W2, bufA);
    k_agg_init<<<16000, 256, 0, stream>>>(bufA, dinv, b2, bufB);
    k_scatter<<<256000, 256, 0, stream>>>(ei, nrm, bufA, bufB);

    // LSTM (relu of layer-2 output fused into read)
    k_lstm<<<250, 512, 0, stream>>>(bufB, Wt, biasc, hbuf);

    // FC head + softmax
    k_fc<<<1000, 256, 0, stream>>>(hbuf, fw1, fb1, fw2, fb2, out);
}